// Round 1
// baseline (482.763 us; speedup 1.0000x reference)
//
#include <hip/hip_runtime.h>
#include <math.h>

#define BB 8
#define NN 4096
#define CC 640
#define SS 77
#define XDIM 768
#define HH 8
#define DH 80
#define BETA 0.5f
#define TAU 0.1f
#define EPSV 1e-8f

typedef _Float16 half_t;
typedef _Float16 h8 __attribute__((ext_vector_type(8)));
typedef float f4 __attribute__((ext_vector_type(4)));

// ---------------- block reduction helper (256 threads) ----------------
__device__ __forceinline__ float blk_reduce(float v, float* red, int tid) {
    red[tid] = v;
    __syncthreads();
#pragma unroll
    for (int st = 128; st > 0; st >>= 1) {
        if (tid < st) red[tid] += red[tid + st];
        __syncthreads();
    }
    float r = red[0];
    __syncthreads();
    return r;
}

// ---------------- pack [Wk|Wv] (fp32 [768,640] each) into fp16 B-fragment stream ----------------
// pW[((ntile*24 + kb)*64 + lane)*8 + j] = W[k = kb*32 + (lane>>4)*8 + j][n = ntile*16 + (lane&15)]
__global__ __launch_bounds__(256) void wkv_pack(const float* __restrict__ Wk,
                                                const float* __restrict__ Wv,
                                                half_t* __restrict__ pW) {
    int idx = blockIdx.x * 256 + threadIdx.x;
    const int TOT = 80 * 24 * 64;
    if (idx >= TOT) return;
    int l  = idx & 63;
    int kb = (idx >> 6) % 24;
    int nt = idx / (24 * 64);
    int n  = nt * 16 + (l & 15);
    int k0 = kb * 32 + ((l >> 4) << 3);
    half_t vals[8];
#pragma unroll
    for (int j = 0; j < 8; j++) {
        float w = (n < CC) ? Wk[(size_t)(k0 + j) * CC + n]
                           : Wv[(size_t)(k0 + j) * CC + (n - CC)];
        vals[j] = (half_t)w;
    }
    *(h8*)(pW + (size_t)idx * 8) = *(h8*)vals;
}

// ---------------- k = enc@Wk, v = enc@Wv via MFMA (M=616 rows, K=768, N=1280) ----------------
__global__ __launch_bounds__(256) void kv_gemm(const float* __restrict__ enc,
                                               const half_t* __restrict__ pW,
                                               float* __restrict__ kmat,
                                               float* __restrict__ vmat) {
    __shared__ half_t sA[16][776];  // 768 + 8 pad (2-way-bank-safe)
    int r0 = blockIdx.x * 16;
    int tid = threadIdx.x;
    for (int e = tid; e < 16 * 768; e += 256) {
        int r = e / 768, k = e - r * 768;
        int bs = r0 + r;
        float v = (bs < BB * SS) ? enc[(size_t)bs * XDIM + k] : 0.f;
        sA[r][k] = (half_t)v;
    }
    __syncthreads();
    int w = tid >> 6, l = tid & 63;
    int arow = l & 15, aq = l >> 4;
    f4 acc[20];
#pragma unroll
    for (int i = 0; i < 20; i++) acc[i] = (f4){0.f, 0.f, 0.f, 0.f};
    for (int kb = 0; kb < 24; kb++) {
        h8 af = *(const h8*)&sA[arow][kb * 32 + aq * 8];
#pragma unroll
        for (int nt = 0; nt < 20; nt++) {
            int ntile = w * 20 + nt;
            h8 bf = *(const h8*)(pW + ((size_t)(ntile * 24 + kb) * 64 + l) * 8);
            acc[nt] = __builtin_amdgcn_mfma_f32_16x16x32_f16(af, bf, acc[nt], 0, 0, 0);
        }
    }
#pragma unroll
    for (int nt = 0; nt < 20; nt++) {
        int col = (w * 20 + nt) * 16 + arow;
#pragma unroll
        for (int i = 0; i < 4; i++) {
            int bs = r0 + aq * 4 + i;
            if (bs < BB * SS) {
                int b = bs / 77, s = bs - b * 77;
                float val = acc[nt][i];
                if (col < CC) kmat[((size_t)b * SS + s) * CC + col] = val;
                else          vmat[((size_t)b * SS + s) * CC + (col - CC)] = val;
            }
        }
    }
}

// ---------------- per-token CORA precompute: G^-1, u_hat, w = beta*a_hat - u_hat ----------------
__global__ __launch_bounds__(256) void erase_pre(const float* __restrict__ target,
                                                 const float* __restrict__ anchor,
                                                 const float* __restrict__ pres,
                                                 float* __restrict__ u_hat,
                                                 float* __restrict__ wvec,
                                                 float* __restrict__ ginv) {
    __shared__ float red[256];
    int s = blockIdx.x, tid = threadIdx.x;
    const float* p0 = pres + (size_t)s * CC;
    const float* p1 = pres + (size_t)(SS + s) * CC;
    const float* tg = target + (size_t)s * CC;
    const float* an = anchor + (size_t)s * CC;
    float x0[3], x1[3], xt[3], xa[3];
    float a00 = 0, a01 = 0, a11 = 0, bt0 = 0, bt1 = 0, ba0 = 0, ba1 = 0;
#pragma unroll
    for (int i = 0; i < 3; i++) {
        int c = tid + i * 256;
        bool ok = c < CC;
        float v0 = ok ? p0[c] : 0.f;
        float v1 = ok ? p1[c] : 0.f;
        float t  = ok ? tg[c] : 0.f;
        float a  = ok ? an[c] : 0.f;
        x0[i] = v0; x1[i] = v1; xt[i] = t; xa[i] = a;
        a00 += v0 * v0; a01 += v0 * v1; a11 += v1 * v1;
        bt0 += v0 * t; bt1 += v1 * t; ba0 += v0 * a; ba1 += v1 * a;
    }
    a00 = blk_reduce(a00, red, tid); a01 = blk_reduce(a01, red, tid);
    a11 = blk_reduce(a11, red, tid);
    bt0 = blk_reduce(bt0, red, tid); bt1 = blk_reduce(bt1, red, tid);
    ba0 = blk_reduce(ba0, red, tid); ba1 = blk_reduce(ba1, red, tid);
    float det = a00 * a11 - a01 * a01;
    float i00 = a11 / det, i01 = -a01 / det, i11 = a00 / det;
    float ct0 = i00 * bt0 + i01 * bt1, ct1 = i01 * bt0 + i11 * bt1;
    float ca0 = i00 * ba0 + i01 * ba1, ca1 = i01 * ba0 + i11 * ba1;
    float ud[3], ad[3], at[3];
    float nu2 = 0, dua = 0;
#pragma unroll
    for (int i = 0; i < 3; i++) {
        ud[i] = xt[i] - ct0 * x0[i] - ct1 * x1[i];
        ad[i] = xa[i] - ca0 * x0[i] - ca1 * x1[i];
        nu2 += ud[i] * ud[i]; dua += ud[i] * ad[i];
    }
    nu2 = blk_reduce(nu2, red, tid); dua = blk_reduce(dua, red, tid);
    float nu = sqrtf(nu2) + EPSV;
    float f = dua / nu;  // u_hat . a_def
    float na2 = 0;
#pragma unroll
    for (int i = 0; i < 3; i++) {
        at[i] = ad[i] - f * (ud[i] / nu);
        na2 += at[i] * at[i];
    }
    na2 = blk_reduce(na2, red, tid);
    float nai = 1.f / (sqrtf(na2) + EPSV);
#pragma unroll
    for (int i = 0; i < 3; i++) {
        int c = tid + i * 256;
        if (c < CC) {
            float uh = ud[i] / nu;
            float ah = at[i] * nai;
            u_hat[(size_t)s * CC + c] = uh;
            wvec[(size_t)s * CC + c] = BETA * ah - uh;
        }
    }
    if (tid == 0) {
        ginv[s * 4 + 0] = i00; ginv[s * 4 + 1] = i01;
        ginv[s * 4 + 2] = i11; ginv[s * 4 + 3] = 0.f;
    }
}

// ---------------- apply erase to v rows (in place) ----------------
__global__ __launch_bounds__(256) void erase_apply(float* __restrict__ vmat,
                                                   const float* __restrict__ pres,
                                                   const float* __restrict__ u_hat,
                                                   const float* __restrict__ wvec,
                                                   const float* __restrict__ ginv) {
    __shared__ float red[256];
    int bs = blockIdx.x, tid = threadIdx.x;
    int b = bs / 77, s = bs - b * 77;
    (void)b;
    float* v = vmat + (size_t)bs * CC;
    const float* p0 = pres + (size_t)s * CC;
    const float* p1 = pres + (size_t)(SS + s) * CC;
    const float* uh = u_hat + (size_t)s * CC;
    float b0 = 0, b1 = 0, tt = 0, n2 = 0;
    for (int c = tid; c < CC; c += 256) {
        float vv = v[c];
        b0 += p0[c] * vv; b1 += p1[c] * vv; tt += uh[c] * vv; n2 += vv * vv;
    }
    b0 = blk_reduce(b0, red, tid); b1 = blk_reduce(b1, red, tid);
    tt = blk_reduce(tt, red, tid); n2 = blk_reduce(n2, red, tid);
    float i00 = ginv[s * 4], i01 = ginv[s * 4 + 1], i11 = ginv[s * 4 + 2];
    float pv2 = b0 * (i00 * b0 + i01 * b1) + b1 * (i01 * b0 + i11 * b1);
    float vf2 = n2 - pv2;
    if (vf2 < 0.f) vf2 = 0.f;
    float denom = sqrtf(vf2) + EPSV;
    bool keep = (fabsf(tt) / denom) < TAU;  // block-uniform branch
    if (!keep) {
        const float* wv = wvec + (size_t)s * CC;
        for (int c = tid; c < CC; c += 256) v[c] += tt * wv[c];
    }
}

// ---------------- M_b[k=c][n=h*77+s] = scale * sum_d Wq[c][h*80+d]*kmat[b][s][h*80+d], packed fp16 ----------------
__global__ __launch_bounds__(320) void m_pack(const float* __restrict__ Wq,
                                              const float* __restrict__ kmat,
                                              half_t* __restrict__ pM) {
    __shared__ float kL[16][80];
    int blk = blockIdx.x;
    int kh = blk & 1;
    int t = (blk >> 1) % 40;
    int b = blk / 80;
    int tid = threadIdx.x;
    int kc = kh * 320 + tid;  // 0..639 : row of Wq
    for (int e = tid; e < 16 * 80; e += 320) {
        int n = e / 80, d = e - n * 80;
        int col = t * 16 + n;
        float val = 0.f;
        if (col < HH * SS) {
            int h = col / 77, s = col - h * 77;
            val = kmat[((size_t)b * SS + s) * CC + h * DH + d];
        }
        kL[n][d] = val;
    }
    __syncthreads();
    int col0 = t * 16;
    int h0 = col0 / 77; if (h0 > 7) h0 = 7;
    int h1 = (col0 + 15) / 77; if (h1 > 7) h1 = 7;
    bool use1[16];
#pragma unroll
    for (int n = 0; n < 16; n++) {
        int h = (col0 + n) / 77; if (h > 7) h = 7;
        use1[n] = (h != h0);
    }
    float out[16];
#pragma unroll
    for (int n = 0; n < 16; n++) out[n] = 0.f;
    const float* wq = Wq + (size_t)kc * CC;
    for (int d = 0; d < 80; d++) {
        float w0 = wq[h0 * 80 + d];
        float w1 = (h1 != h0) ? wq[h1 * 80 + d] : w0;
#pragma unroll
        for (int n = 0; n < 16; n++)
            out[n] = fmaf(use1[n] ? w1 : w0, kL[n][d], out[n]);
    }
    const float qs = 0.11180339887498949f;  // 1/sqrt(80)
    int kb = kc >> 5;
    int lq = ((kc >> 3) & 3) << 4;
    int j = kc & 7;
#pragma unroll
    for (int n = 0; n < 16; n++) {
        int col = col0 + n;
        float val = (col < HH * SS) ? qs * out[n] : 0.f;
        pM[((((size_t)b * 40 + t) * 20 + kb) * 64 + (lq | n)) * 8 + j] = (half_t)val;
    }
}

// ---------------- Vo_b[k=h*77+s][n=c] = sum_d v[b][s][h*80+d]*Wo[h*80+d][c], packed fp16 ----------------
__global__ __launch_bounds__(320) void vo_pack(const float* __restrict__ Wo,
                                               const float* __restrict__ vmat,
                                               half_t* __restrict__ pV) {
    __shared__ float WoL[640][17];
    int blk = blockIdx.x;
    int kh = blk & 1;
    int t = (blk >> 1) % 40;
    int b = blk / 80;
    int tid = threadIdx.x;
    int k = kh * 320 + tid;  // padded s-index 0..639
    for (int e = tid; e < 640 * 16; e += 320) {
        int r = e >> 4, n = e & 15;
        WoL[r][n] = Wo[(size_t)r * CC + t * 16 + n];
    }
    __syncthreads();
    float out[16];
#pragma unroll
    for (int n = 0; n < 16; n++) out[n] = 0.f;
    if (k < HH * SS) {
        int h = k / 77, s = k - h * 77;
        const float* vr = vmat + ((size_t)b * SS + s) * CC + h * DH;
        for (int d = 0; d < 80; d++) {
            float vv = vr[d];
#pragma unroll
            for (int n = 0; n < 16; n++) out[n] = fmaf(vv, WoL[h * 80 + d][n], out[n]);
        }
    }
    int kb = k >> 5;
    int lq = ((k >> 3) & 3) << 4;
    int j = k & 7;
#pragma unroll
    for (int n = 0; n < 16; n++) {
        pV[((((size_t)b * 40 + t) * 20 + kb) * 64 + (lq | n)) * 8 + j] = (half_t)out[n];
    }
}

// ---------------- fused scores -> softmax -> out GEMM ----------------
__global__ __launch_bounds__(256) void attn_main(const float* __restrict__ hidden,
                                                 const half_t* __restrict__ pM,
                                                 const half_t* __restrict__ pV,
                                                 const float* __restrict__ bo,
                                                 float* __restrict__ out) {
    __shared__ half_t sA[32][168];  // hidden chunk (160 k) + 8 pad
    __shared__ half_t sS[32][648];  // scores -> probs (640 padded cols) + 8 pad
    int blk = blockIdx.x;
    int b = blk >> 7;
    int n0 = (blk & 127) << 5;
    int tid = threadIdx.x;
    int w = tid >> 6, l = tid & 63;
    int arow = l & 15, aq = l >> 4;
    const float* Hb = hidden + ((size_t)b * NN + n0) * CC;
    const half_t* pMb = pM + (size_t)b * 409600;
    const half_t* pVb = pV + (size_t)b * 409600;
    f4 acc[2][10];
#pragma unroll
    for (int m = 0; m < 2; m++)
#pragma unroll
        for (int nt = 0; nt < 10; nt++) acc[m][nt] = (f4){0.f, 0.f, 0.f, 0.f};

    // ---- phase A: S[32,640p] = H_tile @ M_b ----
    for (int ch = 0; ch < 4; ch++) {
        if (ch) __syncthreads();
        for (int e = tid; e < 32 * 160; e += 256) {
            int r = e / 160, kk = e - r * 160;
            sA[r][kk] = (half_t)Hb[(size_t)r * CC + ch * 160 + kk];
        }
        __syncthreads();
#pragma unroll
        for (int kb = 0; kb < 5; kb++) {
            h8 af0 = *(const h8*)&sA[arow][kb * 32 + aq * 8];
            h8 af1 = *(const h8*)&sA[16 + arow][kb * 32 + aq * 8];
            int kbg = ch * 5 + kb;
#pragma unroll
            for (int nt = 0; nt < 10; nt++) {
                int ntile = w * 10 + nt;
                h8 bf = *(const h8*)(pMb + ((size_t)(ntile * 20 + kbg) * 64 + l) * 8);
                acc[0][nt] = __builtin_amdgcn_mfma_f32_16x16x32_f16(af0, bf, acc[0][nt], 0, 0, 0);
                acc[1][nt] = __builtin_amdgcn_mfma_f32_16x16x32_f16(af1, bf, acc[1][nt], 0, 0, 0);
            }
        }
    }
    __syncthreads();
    // write scores to LDS (fp16)
#pragma unroll
    for (int m = 0; m < 2; m++)
#pragma unroll
        for (int nt = 0; nt < 10; nt++)
#pragma unroll
            for (int i = 0; i < 4; i++) {
                int r = m * 16 + aq * 4 + i;
                int col = (w * 10 + nt) * 16 + arow;
                sS[r][col] = (half_t)acc[m][nt][i];
            }
    __syncthreads();
    // ---- softmax: one thread per (row, head) ----
    {
        int r = tid >> 3, h = tid & 7;
        half_t* row = &sS[r][h * 77];
        float mx = -1e30f;
        for (int i = 0; i < 77; i++) {
            float v = (float)row[i];
            mx = fmaxf(mx, v);
        }
        float sum = 0.f;
        for (int i = 0; i < 77; i++) {
            float e = __expf((float)row[i] - mx);
            sum += e;
            row[i] = (half_t)e;
        }
        float inv = 1.f / sum;
        for (int i = 0; i < 77; i++) row[i] = (half_t)((float)row[i] * inv);
        if (h == 7) {
#pragma unroll
            for (int i = 616; i < 648; i++) sS[r][i] = (half_t)0.f;
        }
    }
    __syncthreads();
    // ---- phase B: out[32,640] = P @ Vo_b ----
#pragma unroll
    for (int m = 0; m < 2; m++)
#pragma unroll
        for (int nt = 0; nt < 10; nt++) acc[m][nt] = (f4){0.f, 0.f, 0.f, 0.f};
    for (int kb = 0; kb < 20; kb++) {
        h8 pf0 = *(const h8*)&sS[arow][kb * 32 + aq * 8];
        h8 pf1 = *(const h8*)&sS[16 + arow][kb * 32 + aq * 8];
#pragma unroll
        for (int nt = 0; nt < 10; nt++) {
            int ntile = w * 10 + nt;
            h8 vf = *(const h8*)(pVb + ((size_t)(ntile * 20 + kb) * 64 + l) * 8);
            acc[0][nt] = __builtin_amdgcn_mfma_f32_16x16x32_f16(pf0, vf, acc[0][nt], 0, 0, 0);
            acc[1][nt] = __builtin_amdgcn_mfma_f32_16x16x32_f16(pf1, vf, acc[1][nt], 0, 0, 0);
        }
    }
    float* Ob = out + ((size_t)b * NN + n0) * CC;
#pragma unroll
    for (int nt = 0; nt < 10; nt++) {
        int col = (w * 10 + nt) * 16 + arow;
        float bias = bo[col];
#pragma unroll
        for (int m = 0; m < 2; m++)
#pragma unroll
            for (int i = 0; i < 4; i++) {
                int r = m * 16 + aq * 4 + i;
                Ob[(size_t)r * CC + col] = acc[m][nt][i] + bias;
            }
    }
}

extern "C" void kernel_launch(void* const* d_in, const int* in_sizes, int n_in,
                              void* d_out, int out_size, void* d_ws, size_t ws_size,
                              hipStream_t stream) {
    const float* hidden = (const float*)d_in[0];
    const float* enc    = (const float*)d_in[1];
    const float* Wq     = (const float*)d_in[2];
    const float* Wk     = (const float*)d_in[3];
    const float* Wv     = (const float*)d_in[4];
    const float* Wo     = (const float*)d_in[5];
    const float* bo     = (const float*)d_in[6];
    const float* target = (const float*)d_in[7];
    const float* anchor = (const float*)d_in[8];
    const float* pres   = (const float*)d_in[9];
    float* outp = (float*)d_out;
    char* ws = (char*)d_ws;

    // workspace layout (bytes, all 16B aligned)
    float* u_hat = (float*)(ws + 0);          // 77*640 f32
    float* wvec  = (float*)(ws + 197120);     // 77*640 f32
    float* ginv  = (float*)(ws + 394240);     // 77*4  f32
    float* kmat  = (float*)(ws + 395472);     // 8*77*640 f32
    float* vmat  = (float*)(ws + 1972432);    // 8*77*640 f32
    half_t* pW   = (half_t*)(ws + 3549392);   // 768*1280 f16
    half_t* pM   = (half_t*)(ws + 5515472);   // 8*40*20*64*8 f16
    half_t* pV   = (half_t*)(ws + 12069072);  // 8*40*20*64*8 f16

    hipLaunchKernelGGL(wkv_pack, dim3(480), dim3(256), 0, stream, Wk, Wv, pW);
    hipLaunchKernelGGL(erase_pre, dim3(77), dim3(256), 0, stream, target, anchor, pres,
                       u_hat, wvec, ginv);
    hipLaunchKernelGGL(kv_gemm, dim3(39), dim3(256), 0, stream, enc, pW, kmat, vmat);
    hipLaunchKernelGGL(erase_apply, dim3(616), dim3(256), 0, stream, vmat, pres, u_hat,
                       wvec, ginv);
    hipLaunchKernelGGL(m_pack, dim3(640), dim3(320), 0, stream, Wq, kmat, pM);
    hipLaunchKernelGGL(vo_pack, dim3(640), dim3(320), 0, stream, Wo, vmat, pV);
    hipLaunchKernelGGL(attn_main, dim3(1024), dim3(256), 0, stream, hidden, pM, pV, bo, outp);
}

// Round 3
// 373.627 us; speedup vs baseline: 1.2921x; 1.2921x over previous
//
#include <hip/hip_runtime.h>
#include <math.h>

#define BB 8
#define NN 4096
#define CC 640
#define SS 77
#define XDIM 768
#define HH 8
#define DH 80
#define BETA 0.5f
#define TAU 0.1f
#define EPSV 1e-8f

typedef _Float16 half_t;
typedef _Float16 h8 __attribute__((ext_vector_type(8)));
typedef float f4 __attribute__((ext_vector_type(4)));

// ---------------- block reduction helper (256 threads) ----------------
__device__ __forceinline__ float blk_reduce(float v, float* red, int tid) {
    red[tid] = v;
    __syncthreads();
#pragma unroll
    for (int st = 128; st > 0; st >>= 1) {
        if (tid < st) red[tid] += red[tid + st];
        __syncthreads();
    }
    float r = red[0];
    __syncthreads();
    return r;
}

// =======================================================================
// K1: all weight packing + erase_pre, merged.
//  blocks [0,480):    pW   = [Wk|Wv] B-frag stream (K=768, N=1280)
//  blocks [480,720):  pWq  = per-h Wq^T (scaled) B-frag stream (K=96, N=640)
//  blocks [720,960):  pWo  = per-h Wo B-frag stream (K=96, N=640)
//  blocks [960,1037): erase_pre per token s
// =======================================================================
__global__ __launch_bounds__(256) void wpack_all(const float* __restrict__ Wk,
                                                 const float* __restrict__ Wv,
                                                 const float* __restrict__ Wq,
                                                 const float* __restrict__ Wo,
                                                 const float* __restrict__ target,
                                                 const float* __restrict__ anchor,
                                                 const float* __restrict__ pres,
                                                 half_t* __restrict__ pW,
                                                 half_t* __restrict__ pWq,
                                                 half_t* __restrict__ pWo,
                                                 float* __restrict__ u_hat,
                                                 float* __restrict__ wvec,
                                                 float* __restrict__ ginv) {
    __shared__ float red[256];
    int blk = blockIdx.x;
    int tid = threadIdx.x;
    if (blk < 480) {
        int idx = blk * 256 + tid;
        int l = idx & 63;
        int kb = (idx >> 6) % 24;
        int nt = idx / (24 * 64);
        int n = nt * 16 + (l & 15);
        int k0 = kb * 32 + ((l >> 4) << 3);
        half_t vals[8];
#pragma unroll
        for (int j = 0; j < 8; j++) {
            float w = (n < CC) ? Wk[(size_t)(k0 + j) * CC + n]
                               : Wv[(size_t)(k0 + j) * CC + (n - CC)];
            vals[j] = (half_t)w;
        }
        *(h8*)(pW + (size_t)idx * 8) = *(h8*)vals;
        return;
    }
    blk -= 480;
    if (blk < 240) {
        // pWq[h]: B[k=d][n=c] = qs * Wq[c][80h+d], d<80 else 0
        const float qs = 0.11180339887498949f;
        int idx = blk * 256 + tid;
        int l = idx & 63;
        int kb = (idx >> 6) % 3;
        int nt = (idx / (3 * 64)) % 40;
        int h = idx / (40 * 3 * 64);
        int n = nt * 16 + (l & 15);
        int k0 = kb * 32 + ((l >> 4) << 3);
        half_t vals[8];
#pragma unroll
        for (int j = 0; j < 8; j++) {
            int d = k0 + j;
            float w = (d < DH) ? qs * Wq[(size_t)n * CC + h * DH + d] : 0.f;
            vals[j] = (half_t)w;
        }
        *(h8*)(pWq + (size_t)idx * 8) = *(h8*)vals;
        return;
    }
    blk -= 240;
    if (blk < 240) {
        // pWo[h]: B[k=d][n] = Wo[80h+d][n], d<80 else 0
        int idx = blk * 256 + tid;
        int l = idx & 63;
        int kb = (idx >> 6) % 3;
        int nt = (idx / (3 * 64)) % 40;
        int h = idx / (40 * 3 * 64);
        int n = nt * 16 + (l & 15);
        int k0 = kb * 32 + ((l >> 4) << 3);
        half_t vals[8];
#pragma unroll
        for (int j = 0; j < 8; j++) {
            int d = k0 + j;
            float w = (d < DH) ? Wo[(size_t)(h * DH + d) * CC + n] : 0.f;
            vals[j] = (half_t)w;
        }
        *(h8*)(pWo + (size_t)idx * 8) = *(h8*)vals;
        return;
    }
    blk -= 240;
    {
        int s = blk;
        const float* p0 = pres + (size_t)s * CC;
        const float* p1 = pres + (size_t)(SS + s) * CC;
        const float* tg = target + (size_t)s * CC;
        const float* an = anchor + (size_t)s * CC;
        float x0[3], x1[3], xt[3], xa[3];
        float a00 = 0, a01 = 0, a11 = 0, bt0 = 0, bt1 = 0, ba0 = 0, ba1 = 0;
#pragma unroll
        for (int i = 0; i < 3; i++) {
            int c = tid + i * 256;
            bool ok = c < CC;
            float v0 = ok ? p0[c] : 0.f;
            float v1 = ok ? p1[c] : 0.f;
            float t = ok ? tg[c] : 0.f;
            float a = ok ? an[c] : 0.f;
            x0[i] = v0; x1[i] = v1; xt[i] = t; xa[i] = a;
            a00 += v0 * v0; a01 += v0 * v1; a11 += v1 * v1;
            bt0 += v0 * t; bt1 += v1 * t; ba0 += v0 * a; ba1 += v1 * a;
        }
        a00 = blk_reduce(a00, red, tid); a01 = blk_reduce(a01, red, tid);
        a11 = blk_reduce(a11, red, tid);
        bt0 = blk_reduce(bt0, red, tid); bt1 = blk_reduce(bt1, red, tid);
        ba0 = blk_reduce(ba0, red, tid); ba1 = blk_reduce(ba1, red, tid);
        float det = a00 * a11 - a01 * a01;
        float i00 = a11 / det, i01 = -a01 / det, i11 = a00 / det;
        float ct0 = i00 * bt0 + i01 * bt1, ct1 = i01 * bt0 + i11 * bt1;
        float ca0 = i00 * ba0 + i01 * ba1, ca1 = i01 * ba0 + i11 * ba1;
        float ud[3], ad[3], at[3];
        float nu2 = 0, dua = 0;
#pragma unroll
        for (int i = 0; i < 3; i++) {
            ud[i] = xt[i] - ct0 * x0[i] - ct1 * x1[i];
            ad[i] = xa[i] - ca0 * x0[i] - ca1 * x1[i];
            nu2 += ud[i] * ud[i]; dua += ud[i] * ad[i];
        }
        nu2 = blk_reduce(nu2, red, tid); dua = blk_reduce(dua, red, tid);
        float nu = sqrtf(nu2) + EPSV;
        float f = dua / nu;
        float na2 = 0;
#pragma unroll
        for (int i = 0; i < 3; i++) {
            at[i] = ad[i] - f * (ud[i] / nu);
            na2 += at[i] * at[i];
        }
        na2 = blk_reduce(na2, red, tid);
        float nai = 1.f / (sqrtf(na2) + EPSV);
#pragma unroll
        for (int i = 0; i < 3; i++) {
            int c = tid + i * 256;
            if (c < CC) {
                float uh = ud[i] / nu;
                float ah = at[i] * nai;
                u_hat[(size_t)s * CC + c] = uh;
                wvec[(size_t)s * CC + c] = BETA * ah - uh;
            }
        }
        if (tid == 0) {
            ginv[s * 4 + 0] = i00; ginv[s * 4 + 1] = i01;
            ginv[s * 4 + 2] = i11; ginv[s * 4 + 3] = 0.f;
        }
    }
}

// ---------------- k = enc@Wk, v = enc@Wv via MFMA (M=616 rows, K=768, N=1280) ----------------
__global__ __launch_bounds__(256) void kv_gemm(const float* __restrict__ enc,
                                               const half_t* __restrict__ pW,
                                               float* __restrict__ kmat,
                                               float* __restrict__ vmat) {
    __shared__ half_t sA[16][776];
    int r0 = blockIdx.x * 16;
    int tid = threadIdx.x;
    for (int e = tid; e < 16 * 768; e += 256) {
        int r = e / 768, k = e - r * 768;
        int bs = r0 + r;
        float v = (bs < BB * SS) ? enc[(size_t)bs * XDIM + k] : 0.f;
        sA[r][k] = (half_t)v;
    }
    __syncthreads();
    int w = tid >> 6, l = tid & 63;
    int arow = l & 15, aq = l >> 4;
    f4 acc[20];
#pragma unroll
    for (int i = 0; i < 20; i++) acc[i] = (f4){0.f, 0.f, 0.f, 0.f};
    for (int kb = 0; kb < 24; kb++) {
        h8 af = *(const h8*)&sA[arow][kb * 32 + aq * 8];
#pragma unroll
        for (int nt = 0; nt < 20; nt++) {
            int ntile = w * 20 + nt;
            h8 bf = *(const h8*)(pW + ((size_t)(ntile * 24 + kb) * 64 + l) * 8);
            acc[nt] = __builtin_amdgcn_mfma_f32_16x16x32_f16(af, bf, acc[nt], 0, 0, 0);
        }
    }
#pragma unroll
    for (int nt = 0; nt < 20; nt++) {
        int col = (w * 20 + nt) * 16 + arow;
#pragma unroll
        for (int i = 0; i < 4; i++) {
            int bs = r0 + aq * 4 + i;
            if (bs < BB * SS) {
                float val = acc[nt][i];
                if (col < CC) kmat[(size_t)bs * CC + col] = val;
                else          vmat[(size_t)bs * CC + (col - CC)] = val;
            }
        }
    }
}

// ---------------- apply erase to v rows (in place) ----------------
__global__ __launch_bounds__(256) void erase_apply(float* __restrict__ vmat,
                                                   const float* __restrict__ pres,
                                                   const float* __restrict__ u_hat,
                                                   const float* __restrict__ wvec,
                                                   const float* __restrict__ ginv) {
    __shared__ float red[256];
    int bs = blockIdx.x, tid = threadIdx.x;
    int s = bs % 77;
    float* v = vmat + (size_t)bs * CC;
    const float* p0 = pres + (size_t)s * CC;
    const float* p1 = pres + (size_t)(SS + s) * CC;
    const float* uh = u_hat + (size_t)s * CC;
    float b0 = 0, b1 = 0, tt = 0, n2 = 0;
    for (int c = tid; c < CC; c += 256) {
        float vv = v[c];
        b0 += p0[c] * vv; b1 += p1[c] * vv; tt += uh[c] * vv; n2 += vv * vv;
    }
    b0 = blk_reduce(b0, red, tid); b1 = blk_reduce(b1, red, tid);
    tt = blk_reduce(tt, red, tid); n2 = blk_reduce(n2, red, tid);
    float i00 = ginv[s * 4], i01 = ginv[s * 4 + 1], i11 = ginv[s * 4 + 2];
    float pv2 = b0 * (i00 * b0 + i01 * b1) + b1 * (i01 * b0 + i11 * b1);
    float vf2 = n2 - pv2;
    if (vf2 < 0.f) vf2 = 0.f;
    float denom = sqrtf(vf2) + EPSV;
    bool keep = (fabsf(tt) / denom) < TAU;
    if (!keep) {
        const float* wv = wvec + (size_t)s * CC;
        for (int c = tid; c < CC; c += 256) v[c] += tt * wv[c];
    }
}

// =======================================================================
// K4: hsgemm — per (b,h): C[80,640] = X[80,80] @ W_h[80,640] via MFMA,
// scatter fp16 into attn B-frag streams pM / pV. Score coordinate = h*80+s
// (head-aligned padding; s in [77,80) written as 0).
//  job 0: X = k_bh -> pM (attn k-dim = c,      n-dim = h*80+s)
//  job 1: X = v_bh -> pV (attn k-dim = h*80+s, n-dim = c)
// =======================================================================
__global__ __launch_bounds__(512) void hsgemm(const float* __restrict__ kmat,
                                              const float* __restrict__ vmat,
                                              const half_t* __restrict__ pWq,
                                              const half_t* __restrict__ pWo,
                                              half_t* __restrict__ pM,
                                              half_t* __restrict__ pV) {
    __shared__ half_t sX[80][104];
    int blk = blockIdx.x;
    int b = blk & 7;
    int h = (blk >> 3) & 7;
    int job = blk >> 6;
    const float* src = job ? vmat : kmat;
    const half_t* pWx = job ? pWo : pWq;
    int tid = threadIdx.x;
    for (int e = tid; e < 80 * 104; e += 512) {
        int r = e / 104, d = e - r * 104;
        float v = 0.f;
        if (r < SS && d < DH) v = src[((size_t)b * SS + r) * CC + h * DH + d];
        sX[r][d] = (half_t)v;
    }
    __syncthreads();
    int w = tid >> 6, l = tid & 63;
    int arow = l & 15, aq = l >> 4;
    f4 acc[5][5];
#pragma unroll
    for (int mt = 0; mt < 5; mt++)
#pragma unroll
        for (int nn = 0; nn < 5; nn++) acc[mt][nn] = (f4){0.f, 0.f, 0.f, 0.f};
#pragma unroll
    for (int kb = 0; kb < 3; kb++) {
        h8 af[5];
#pragma unroll
        for (int mt = 0; mt < 5; mt++)
            af[mt] = *(const h8*)&sX[mt * 16 + arow][kb * 32 + aq * 8];
#pragma unroll
        for (int nn = 0; nn < 5; nn++) {
            int nt = w * 5 + nn;
            h8 bf = *(const h8*)(pWx + ((size_t)((h * 40 + nt) * 3 + kb) * 64 + l) * 8);
#pragma unroll
            for (int mt = 0; mt < 5; mt++)
                acc[mt][nn] = __builtin_amdgcn_mfma_f32_16x16x32_f16(af[mt], bf, acc[mt][nn], 0, 0, 0);
        }
    }
    half_t* dst = (job ? pV : pM) + (size_t)b * 409600;
#pragma unroll
    for (int mt = 0; mt < 5; mt++) {
#pragma unroll
        for (int nn = 0; nn < 5; nn++) {
#pragma unroll
            for (int i = 0; i < 4; i++) {
                int sp = mt * 16 + aq * 4 + i;       // 0..79
                int c = (w * 5 + nn) * 16 + arow;
                float fv = (sp < SS) ? acc[mt][nn][i] : 0.f;
                int na, ka;
                if (job == 0) { na = h * 80 + sp; ka = c; }
                else          { ka = h * 80 + sp; na = c; }
                size_t idx = ((size_t)((na >> 4) * 20 + (ka >> 5)) * 64 +
                              ((((ka >> 3) & 3) << 4) | (na & 15))) * 8 + (ka & 7);
                dst[idx] = (half_t)fv;
            }
        }
    }
}

// =======================================================================
// K5: fused scores -> per-head register softmax -> out GEMM. M=64 rows.
// grid 512: b = blk&7 (XCD-pinned), row tile = blk>>3. 512 threads = 8 waves:
// wm = w>>2 picks 32-row half, wn = w&3 picks 160-col quarter = 2 heads.
// Score col = h*80 + s; head h = wn*2 + nt/5; s = (nt%5)*16 + arow.
// =======================================================================
__global__ __launch_bounds__(512) void attn_main(const float* __restrict__ hidden,
                                                 const half_t* __restrict__ pM,
                                                 const half_t* __restrict__ pV,
                                                 const float* __restrict__ bo,
                                                 float* __restrict__ out) {
    __shared__ half_t sP[64][648];  // hidden stage -> P station (reused)
    int blk = blockIdx.x;
    int b = blk & 7;
    int n0 = (blk >> 3) << 6;
    int tid = threadIdx.x;
    int w = tid >> 6, l = tid & 63;
    int wm = w >> 2, wn = w & 3;
    int arow = l & 15, aq = l >> 4;
    const float* Hb = hidden + ((size_t)b * NN + n0) * CC;
    const half_t* pMb = pM + (size_t)b * 409600;
    const half_t* pVb = pV + (size_t)b * 409600;

    // ---- stage hidden 64x640 -> fp16, vectorized ----
#pragma unroll
    for (int it = 0; it < 10; it++) {
        int e = (tid + it * 512) * 8;
        int r = e / 640, c = e - r * 640;
        const float* src = Hb + (size_t)r * CC + c;
        half_t v[8];
#pragma unroll
        for (int j = 0; j < 8; j++) v[j] = (half_t)src[j];
        *(h8*)&sP[r][c] = *(h8*)v;
    }
    __syncthreads();

    // ---- phase A: scores = H_tile @ M_b ----
    f4 acc[2][10];
#pragma unroll
    for (int mi = 0; mi < 2; mi++)
#pragma unroll
        for (int nt = 0; nt < 10; nt++) acc[mi][nt] = (f4){0.f, 0.f, 0.f, 0.f};
    for (int kbg = 0; kbg < 20; kbg++) {
        h8 a0 = *(const h8*)&sP[wm * 32 + arow][kbg * 32 + aq * 8];
        h8 a1 = *(const h8*)&sP[wm * 32 + 16 + arow][kbg * 32 + aq * 8];
#pragma unroll
        for (int nt = 0; nt < 10; nt++) {
            h8 bf = *(const h8*)(pMb + ((size_t)((wn * 10 + nt) * 20 + kbg) * 64 + l) * 8);
            acc[0][nt] = __builtin_amdgcn_mfma_f32_16x16x32_f16(a0, bf, acc[0][nt], 0, 0, 0);
            acc[1][nt] = __builtin_amdgcn_mfma_f32_16x16x32_f16(a1, bf, acc[1][nt], 0, 0, 0);
        }
    }

    // ---- per-head softmax, fully in registers ----
    // lane holds cols {nt*16+arow}; nt<5 -> head 2wn, nt>=5 -> head 2wn+1;
    // s_local = (nt%5)*16 + arow; valid iff s_local < 77.
    float pmax[2][2][4];
#pragma unroll
    for (int mi = 0; mi < 2; mi++)
#pragma unroll
        for (int hl = 0; hl < 2; hl++)
#pragma unroll
            for (int i = 0; i < 4; i++) pmax[mi][hl][i] = -1e30f;
#pragma unroll
    for (int mi = 0; mi < 2; mi++)
#pragma unroll
        for (int nt = 0; nt < 10; nt++) {
            int hl = nt / 5;
            int sl = (nt % 5) * 16 + arow;
            if (sl < SS) {
#pragma unroll
                for (int i = 0; i < 4; i++)
                    pmax[mi][hl][i] = fmaxf(pmax[mi][hl][i], acc[mi][nt][i]);
            }
        }
#pragma unroll
    for (int st = 1; st < 16; st <<= 1) {
#pragma unroll
        for (int mi = 0; mi < 2; mi++)
#pragma unroll
            for (int hl = 0; hl < 2; hl++)
#pragma unroll
                for (int i = 0; i < 4; i++)
                    pmax[mi][hl][i] = fmaxf(pmax[mi][hl][i], __shfl_xor(pmax[mi][hl][i], st, 64));
    }
    float psum[2][2][4];
#pragma unroll
    for (int mi = 0; mi < 2; mi++)
#pragma unroll
        for (int hl = 0; hl < 2; hl++)
#pragma unroll
            for (int i = 0; i < 4; i++) psum[mi][hl][i] = 0.f;
#pragma unroll
    for (int mi = 0; mi < 2; mi++)
#pragma unroll
        for (int nt = 0; nt < 10; nt++) {
            int hl = nt / 5;
            int sl = (nt % 5) * 16 + arow;
            bool ok = sl < SS;
#pragma unroll
            for (int i = 0; i < 4; i++) {
                float e = ok ? __expf(acc[mi][nt][i] - pmax[mi][hl][i]) : 0.f;
                acc[mi][nt][i] = e;
                psum[mi][hl][i] += e;
            }
        }
#pragma unroll
    for (int st = 1; st < 16; st <<= 1) {
#pragma unroll
        for (int mi = 0; mi < 2; mi++)
#pragma unroll
            for (int hl = 0; hl < 2; hl++)
#pragma unroll
                for (int i = 0; i < 4; i++)
                    psum[mi][hl][i] += __shfl_xor(psum[mi][hl][i], st, 64);
    }
    float rinv[2][2][4];
#pragma unroll
    for (int mi = 0; mi < 2; mi++)
#pragma unroll
        for (int hl = 0; hl < 2; hl++)
#pragma unroll
            for (int i = 0; i < 4; i++) rinv[mi][hl][i] = 1.f / psum[mi][hl][i];

    __syncthreads();  // all waves done reading sP (hidden) in phase A
    // write P (fp16) into sP
#pragma unroll
    for (int mi = 0; mi < 2; mi++)
#pragma unroll
        for (int nt = 0; nt < 10; nt++) {
            int col = wn * 160 + nt * 16 + arow;
            int hl = nt / 5;
#pragma unroll
            for (int i = 0; i < 4; i++) {
                int r = wm * 32 + mi * 16 + aq * 4 + i;
                sP[r][col] = (half_t)(acc[mi][nt][i] * rinv[mi][hl][i]);
            }
        }
    __syncthreads();

    // ---- phase B: out = P @ Vo_b ----
    f4 acc2[2][10];
#pragma unroll
    for (int mi = 0; mi < 2; mi++)
#pragma unroll
        for (int nt = 0; nt < 10; nt++) acc2[mi][nt] = (f4){0.f, 0.f, 0.f, 0.f};
    for (int kb = 0; kb < 20; kb++) {
        h8 p0 = *(const h8*)&sP[wm * 32 + arow][kb * 32 + aq * 8];
        h8 p1 = *(const h8*)&sP[wm * 32 + 16 + arow][kb * 32 + aq * 8];
#pragma unroll
        for (int nt = 0; nt < 10; nt++) {
            h8 vf = *(const h8*)(pVb + ((size_t)((wn * 10 + nt) * 20 + kb) * 64 + l) * 8);
            acc2[0][nt] = __builtin_amdgcn_mfma_f32_16x16x32_f16(p0, vf, acc2[0][nt], 0, 0, 0);
            acc2[1][nt] = __builtin_amdgcn_mfma_f32_16x16x32_f16(p1, vf, acc2[1][nt], 0, 0, 0);
        }
    }
    float* Ob = out + ((size_t)b * NN + n0) * CC;
#pragma unroll
    for (int nt = 0; nt < 10; nt++) {
        int col = (wn * 10 + nt) * 16 + arow;
        float bias = bo[col];
#pragma unroll
        for (int mi = 0; mi < 2; mi++)
#pragma unroll
            for (int i = 0; i < 4; i++) {
                int r = wm * 32 + mi * 16 + aq * 4 + i;
                Ob[(size_t)r * CC + col] = acc2[mi][nt][i] + bias;
            }
    }
}

extern "C" void kernel_launch(void* const* d_in, const int* in_sizes, int n_in,
                              void* d_out, int out_size, void* d_ws, size_t ws_size,
                              hipStream_t stream) {
    const float* hidden = (const float*)d_in[0];
    const float* enc    = (const float*)d_in[1];
    const float* Wq     = (const float*)d_in[2];
    const float* Wk     = (const float*)d_in[3];
    const float* Wv     = (const float*)d_in[4];
    const float* Wo     = (const float*)d_in[5];
    const float* bo     = (const float*)d_in[6];
    const float* target = (const float*)d_in[7];
    const float* anchor = (const float*)d_in[8];
    const float* pres   = (const float*)d_in[9];
    float* outp = (float*)d_out;
    char* ws = (char*)d_ws;

    float* u_hat = (float*)(ws + 0);          // 77*640 f32   -> 197120
    float* wvec  = (float*)(ws + 197120);     // 77*640 f32   -> 394240
    float* ginv  = (float*)(ws + 394240);     // 77*4 f32 pad -> 395520
    float* kmat  = (float*)(ws + 395520);     // 616*640 f32  -> 1972480
    float* vmat  = (float*)(ws + 1972480);    // 616*640 f32  -> 3549440
    half_t* pW   = (half_t*)(ws + 3549440);   // 768*1280 f16 -> 5515520
    half_t* pWq  = (half_t*)(ws + 5515520);   // 8*40*3*64*8  -> 6498560
    half_t* pWo  = (half_t*)(ws + 6498560);   // 8*40*3*64*8  -> 7481600
    half_t* pM   = (half_t*)(ws + 7481600);   // 8*409600 f16 -> 14035200
    half_t* pV   = (half_t*)(ws + 14035200);  // 8*409600 f16 -> 20588800

    hipLaunchKernelGGL(wpack_all, dim3(1037), dim3(256), 0, stream, Wk, Wv, Wq, Wo,
                       target, anchor, pres, pW, pWq, pWo, u_hat, wvec, ginv);
    hipLaunchKernelGGL(kv_gemm, dim3(39), dim3(256), 0, stream, enc, pW, kmat, vmat);
    hipLaunchKernelGGL(erase_apply, dim3(616), dim3(256), 0, stream, vmat, pres, u_hat,
                       wvec, ginv);
    hipLaunchKernelGGL(hsgemm, dim3(128), dim3(512), 0, stream, kmat, vmat, pWq, pWo, pM, pV);
    hipLaunchKernelGGL(attn_main, dim3(512), dim3(512), 0, stream, hidden, pM, pV, bo, outp);
}